// Round 1
// baseline (117.685 us; speedup 1.0000x reference)
//
#include <hip/hip_runtime.h>

#define NPIX 5184   // 72*72
#define KDIM 256
#define OUTHW 224

typedef __bf16 bf16x8 __attribute__((ext_vector_type(8)));
typedef float  f32x4  __attribute__((ext_vector_type(4)));

__device__ inline unsigned short f2bf(float f) {
    unsigned int b = __float_as_uint(f);
    b += 0x7FFFu + ((b >> 16) & 1u);     // round-to-nearest-even
    return (unsigned short)(b >> 16);
}
// monotonic float<->uint mapping so atomicMax(uint) orders floats (incl. negatives)
__device__ inline unsigned int fmono(float f) {
    unsigned int b = __float_as_uint(f);
    return b ^ ((b >> 31) ? 0xFFFFFFFFu : 0x80000000u);
}
__device__ inline float funmono(unsigned int u) {
    unsigned int b = u ^ ((u >> 31) ? 0x80000000u : 0xFFFFFFFFu);
    return __uint_as_float(b);
}

__global__ void init_ws(float* acc, unsigned int* max_u) {
    int i = blockIdx.x * blockDim.x + threadIdx.x;
    if (i < 2 * NPIX) acc[i] = 0.0f;
    if (i == 0) *max_u = 0u;   // decodes to a huge negative float
}

// One pass: D = A * B^T (5184x5184, K=256) tiled 64x64; per tile accumulate
// relu row/col sums (atomicAdd) and global max (one atomicMax per block).
__global__ __launch_bounds__(256, 2) void gemm_reduce(
        const float* __restrict__ A, const float* __restrict__ B,
        float* __restrict__ row_sum, float* __restrict__ col_sum,
        unsigned int* __restrict__ max_u) {
    __shared__ char lds[2 * 64 * 512];      // A-tile + B-tile, bf16, 64 rows x 256 K
    char* As = lds;
    char* Bs = lds + 64 * 512;

    const int tid  = threadIdx.x;
    const int brow = blockIdx.x * 64;
    const int bcol = blockIdx.y * 64;

    // ---- stage fp32 -> bf16 into LDS with XOR swizzle (kills 16-way conflicts) ----
    const float4* Ag = reinterpret_cast<const float4*>(A) + (size_t)brow * 64;
    const float4* Bg = reinterpret_cast<const float4*>(B) + (size_t)bcol * 64;
    #pragma unroll
    for (int it = 0; it < 16; ++it) {
        int idx = it * 256 + tid;          // float4 index within 64x64-float4 tile
        int r   = idx >> 6;
        int c4  = idx & 63;
        float4 av = Ag[r * 64 + c4];
        float4 bv = Bg[r * 64 + c4];
        ushort4 au = { f2bf(av.x), f2bf(av.y), f2bf(av.z), f2bf(av.w) };
        ushort4 bu = { f2bf(bv.x), f2bf(bv.y), f2bf(bv.z), f2bf(bv.w) };
        int boff = (r << 9) + (((c4 << 3)) ^ ((r & 7) << 4));
        *reinterpret_cast<ushort4*>(As + boff) = au;
        *reinterpret_cast<ushort4*>(Bs + boff) = bu;
    }
    __syncthreads();

    // ---- MFMA: 4 waves in 2x2, each wave computes a 32x32 output sub-tile ----
    const int lane = tid & 63;
    const int wave = tid >> 6;
    const int wr = wave >> 1;
    const int wc = wave & 1;
    const int lr = lane & 15;
    const int lkb = (lane >> 4) << 4;      // k byte offset of this lane group (8 bf16 = 16B)

    const int ar0 = wr * 32 + lr;          // A rows (m=0 / m=1 is +16)
    const int br0 = wc * 32 + lr;          // B rows (n=0 / n=1 is +16)
    const int swa = (ar0 & 7) << 4;        // same for ar0+16
    const int swb = (br0 & 7) << 4;

    f32x4 acc[2][2] = {};
    #pragma unroll
    for (int ks = 0; ks < 8; ++ks) {
        int cb = ks * 64 + lkb;
        bf16x8 a0 = *reinterpret_cast<const bf16x8*>(As + (ar0 << 9)          + (cb ^ swa));
        bf16x8 a1 = *reinterpret_cast<const bf16x8*>(As + ((ar0 + 16) << 9)   + (cb ^ swa));
        bf16x8 b0 = *reinterpret_cast<const bf16x8*>(Bs + (br0 << 9)          + (cb ^ swb));
        bf16x8 b1 = *reinterpret_cast<const bf16x8*>(Bs + ((br0 + 16) << 9)   + (cb ^ swb));
        acc[0][0] = __builtin_amdgcn_mfma_f32_16x16x32_bf16(a0, b0, acc[0][0], 0, 0, 0);
        acc[0][1] = __builtin_amdgcn_mfma_f32_16x16x32_bf16(a0, b1, acc[0][1], 0, 0, 0);
        acc[1][0] = __builtin_amdgcn_mfma_f32_16x16x32_bf16(a1, b0, acc[1][0], 0, 0, 0);
        acc[1][1] = __builtin_amdgcn_mfma_f32_16x16x32_bf16(a1, b1, acc[1][1], 0, 0, 0);
    }
    // C/D layout (m89-verified): col = lane&15, row = (lane>>4)*4 + reg

    // ---- tile max (raw, pre-relu) ----
    float mx = -3.4e38f;
    #pragma unroll
    for (int m = 0; m < 2; ++m)
        #pragma unroll
        for (int n = 0; n < 2; ++n)
            #pragma unroll
            for (int r = 0; r < 4; ++r)
                mx = fmaxf(mx, acc[m][n][r]);
    #pragma unroll
    for (int off = 32; off >= 1; off >>= 1)
        mx = fmaxf(mx, __shfl_xor(mx, off));

    // ---- col sums: reduce over rows (m, reg) then lane groups ----
    float cs0 = 0.0f, cs1 = 0.0f;
    #pragma unroll
    for (int m = 0; m < 2; ++m)
        #pragma unroll
        for (int r = 0; r < 4; ++r) {
            cs0 += fmaxf(acc[m][0][r], 0.0f);
            cs1 += fmaxf(acc[m][1][r], 0.0f);
        }
    cs0 += __shfl_xor(cs0, 16); cs0 += __shfl_xor(cs0, 32);
    cs1 += __shfl_xor(cs1, 16); cs1 += __shfl_xor(cs1, 32);
    if (lane < 16) {
        atomicAdd(&col_sum[bcol + wc * 32 + lane],      cs0);
        atomicAdd(&col_sum[bcol + wc * 32 + 16 + lane], cs1);
    }

    // ---- row sums: per-lane partial over n, reduce across the 16 col-lanes ----
    float rs[8];
    #pragma unroll
    for (int m = 0; m < 2; ++m)
        #pragma unroll
        for (int r = 0; r < 4; ++r)
            rs[m * 4 + r] = fmaxf(acc[m][0][r], 0.0f) + fmaxf(acc[m][1][r], 0.0f);
    #pragma unroll
    for (int off = 1; off <= 8; off <<= 1)
        #pragma unroll
        for (int j = 0; j < 8; ++j)
            rs[j] += __shfl_xor(rs[j], off);
    if ((lane & 15) == 0) {
        int rbase = brow + wr * 32 + (lane >> 4) * 4;
        #pragma unroll
        for (int m = 0; m < 2; ++m)
            #pragma unroll
            for (int r = 0; r < 4; ++r)
                atomicAdd(&row_sum[rbase + m * 16 + r], rs[m * 4 + r]);
    }

    // ---- one atomicMax per block (reuse LDS after all waves done reading) ----
    __syncthreads();
    float* smax = reinterpret_cast<float*>(lds);
    if (lane == 0) smax[wave] = mx;
    __syncthreads();
    if (tid == 0) {
        float m4 = fmaxf(fmaxf(smax[0], smax[1]), fmaxf(smax[2], smax[3]));
        atomicMax(max_u, fmono(m4));
    }
}

// Bilinear resize 2x72x72 -> 2x224x224 with final /max (resize is linear).
__global__ void finalize(const float* __restrict__ row_sum,
                         const float* __restrict__ col_sum,
                         const unsigned int* __restrict__ max_u,
                         float* __restrict__ out) {
    int o = blockIdx.x * blockDim.x + threadIdx.x;
    if (o >= 2 * OUTHW * OUTHW) return;
    int img = o / (OUTHW * OUTHW);
    int rem = o % (OUTHW * OUTHW);
    int oy = rem / OUTHW, ox = rem % OUTHW;
    const float* src = (img == 0) ? row_sum : col_sum;
    float inv = 1.0f / funmono(*max_u);

    const float s = 72.0f / 224.0f;
    float ys = fmaxf(((float)oy + 0.5f) * s - 0.5f, 0.0f);
    float xs = fmaxf(((float)ox + 0.5f) * s - 0.5f, 0.0f);
    int y0 = (int)floorf(ys), x0 = (int)floorf(xs);
    int y1 = min(y0 + 1, 71), x1 = min(x0 + 1, 71);
    float wy = ys - (float)y0, wx = xs - (float)x0;

    float a = src[y0 * 72 + x0], b = src[y0 * 72 + x1];
    float c = src[y1 * 72 + x0], d = src[y1 * 72 + x1];
    float v = a * (1.0f - wy) * (1.0f - wx) + b * (1.0f - wy) * wx
            + c * wy * (1.0f - wx)          + d * wy * wx;
    out[o] = v * inv;
}

extern "C" void kernel_launch(void* const* d_in, const int* in_sizes, int n_in,
                              void* d_out, int out_size, void* d_ws, size_t ws_size,
                              hipStream_t stream) {
    const float* X = (const float*)d_in[0];
    const float* A = X;                         // x[0]: [5184, 256]
    const float* B = X + (size_t)NPIX * KDIM;   // x[1]: [5184, 256]

    float* row_sum        = (float*)d_ws;
    float* col_sum        = row_sum + NPIX;
    unsigned int* max_u   = (unsigned int*)(col_sum + NPIX);
    float* out            = (float*)d_out;

    init_ws<<<(2 * NPIX + 255) / 256, 256, 0, stream>>>(row_sum, max_u);
    gemm_reduce<<<dim3(81, 81), 256, 0, stream>>>(A, B, row_sum, col_sum, max_u);
    finalize<<<(2 * OUTHW * OUTHW + 255) / 256, 256, 0, stream>>>(row_sum, col_sum, max_u, out);
}

// Round 2
// 59.167 us; speedup vs baseline: 1.9890x; 1.9890x over previous
//
#include <hip/hip_runtime.h>

#define NPIX 5184   // 72*72
#define KDIM 256
#define OUTHW 224
#define TILE 128
#define GRID_T 41   // ceil(5184/128)

typedef __bf16 bf16x8 __attribute__((ext_vector_type(8)));
typedef float  f32x4  __attribute__((ext_vector_type(4)));

__device__ inline unsigned short f2bf(float f) {
    unsigned int b = __float_as_uint(f);
    b += 0x7FFFu + ((b >> 16) & 1u);     // round-to-nearest-even
    return (unsigned short)(b >> 16);
}
// monotonic float<->uint mapping so atomicMax(uint) orders floats
__device__ inline unsigned int fmono(float f) {
    unsigned int b = __float_as_uint(f);
    return b ^ ((b >> 31) ? 0xFFFFFFFFu : 0x80000000u);
}
__device__ inline float funmono(unsigned int u) {
    unsigned int b = u ^ ((u >> 31) ? 0x80000000u : 0xFFFFFFFFu);
    return __uint_as_float(b);
}

__global__ void init_ws(float* acc, unsigned int* max_u) {
    int i = blockIdx.x * blockDim.x + threadIdx.x;
    if (i < 2 * NPIX) acc[i] = 0.0f;
    if (i == 0) *max_u = 0u;
}

// fp32 -> bf16 for both matrices (contiguous), fused with sums/max init.
__global__ void convert_bf16(const float* __restrict__ x, unsigned short* __restrict__ y,
                             float* __restrict__ sums, unsigned int* __restrict__ max_u,
                             int n4) {
    int i = blockIdx.x * blockDim.x + threadIdx.x;
    if (i < 2 * NPIX) sums[i] = 0.0f;
    if (i == 0) *max_u = 0u;
    if (i >= n4) return;
    float4 v = reinterpret_cast<const float4*>(x)[i];
    ushort4 u = { f2bf(v.x), f2bf(v.y), f2bf(v.z), f2bf(v.w) };
    reinterpret_cast<ushort4*>(y)[i] = u;
}

// D = A*B^T (5184^2, K=256) in 128x128 tiles; fused relu row/col sums + max.
// LDS layout: [128 rows][512 B], 16B chunk c of row r stored at chunk c^(r&7).
template<bool BF16IN>
__global__ __launch_bounds__(512) void gemm_reduce(
        const void* __restrict__ Ain, const void* __restrict__ Bin,
        float* __restrict__ row_sum, float* __restrict__ col_sum,
        unsigned int* __restrict__ max_u) {
    __shared__ char lds[2 * TILE * 512];      // 128 KiB
    char* As = lds;
    char* Bs = lds + TILE * 512;

    // bijective XCD chunk swizzle: each XCD gets ~210 consecutive tiles
    const int nwg = 1681, wg = blockIdx.x;
    const int q = nwg >> 3, r8 = nwg & 7;
    const int xcd = wg & 7, cidx = wg >> 3;
    const int swz = (xcd < r8) ? xcd * (q + 1) + cidx
                               : r8 * (q + 1) + (xcd - r8) * q + cidx;
    const int bx = swz % GRID_T;              // row tile
    const int by = swz / GRID_T;              // col tile
    const int brow = bx * TILE, bcol = by * TILE;

    const int tid  = threadIdx.x;
    const int wave = tid >> 6, lane = tid & 63;

    if (BF16IN) {
        const char* Ag = (const char*)Ain;
        const char* Bg = (const char*)Bin;
        #pragma unroll
        for (int i = 0; i < 8; ++i) {         // 16 rows per iteration
            int p    = i * 8192 + tid * 16;   // this thread's LDS byte position
            int rloc = p >> 9;
            int c    = (p >> 4) & 31;
            int cs   = c ^ (rloc & 7);        // pre-swizzled source chunk
            // validity is uniform per 16-row group (boundary at 64-row offset)
            if (brow + rloc < NPIX) {
                __builtin_amdgcn_global_load_lds(
                    (const __attribute__((address_space(1))) unsigned int*)
                        (Ag + (long)(brow + rloc) * 512 + (cs << 4)),
                    (__attribute__((address_space(3))) unsigned int*)
                        (As + i * 8192 + wave * 1024), 16, 0, 0);
            } else {
                *reinterpret_cast<f32x4*>(As + p) = f32x4{0.f, 0.f, 0.f, 0.f};
            }
            if (bcol + rloc < NPIX) {
                __builtin_amdgcn_global_load_lds(
                    (const __attribute__((address_space(1))) unsigned int*)
                        (Bg + (long)(bcol + rloc) * 512 + (cs << 4)),
                    (__attribute__((address_space(3))) unsigned int*)
                        (Bs + i * 8192 + wave * 1024), 16, 0, 0);
            } else {
                *reinterpret_cast<f32x4*>(Bs + p) = f32x4{0.f, 0.f, 0.f, 0.f};
            }
        }
    } else {
        const float4* Ag = (const float4*)Ain;
        const float4* Bg = (const float4*)Bin;
        #pragma unroll
        for (int i = 0; i < 16; ++i) {
            int idx4 = i * 512 + tid;
            int rloc = idx4 >> 6;
            int c4   = idx4 & 63;
            int boff = (rloc << 9) + ((c4 << 3) ^ ((rloc & 7) << 4));
            float4 av = (brow + rloc < NPIX) ? Ag[(long)(brow + rloc) * 64 + c4]
                                             : float4{0.f, 0.f, 0.f, 0.f};
            float4 bv = (bcol + rloc < NPIX) ? Bg[(long)(bcol + rloc) * 64 + c4]
                                             : float4{0.f, 0.f, 0.f, 0.f};
            ushort4 au = { f2bf(av.x), f2bf(av.y), f2bf(av.z), f2bf(av.w) };
            ushort4 bu = { f2bf(bv.x), f2bf(bv.y), f2bf(bv.z), f2bf(bv.w) };
            *reinterpret_cast<ushort4*>(As + boff) = au;
            *reinterpret_cast<ushort4*>(Bs + boff) = bu;
        }
    }
    __syncthreads();

    // ---- 8 waves in 2x4; each wave computes a 64x32 output sub-tile ----
    const int wr = wave >> 2;    // 0..1
    const int wc = wave & 3;     // 0..3
    const int lr = lane & 15;
    const int lg = lane >> 4;    // 0..3

    f32x4 acc[4][2] = {};
    #pragma unroll
    for (int ks = 0; ks < 8; ++ks) {
        int kc = ks * 4 + lg;                 // 16B k-chunk index
        bf16x8 a[4], b[2];
        #pragma unroll
        for (int m = 0; m < 4; ++m) {
            int rr = wr * 64 + m * 16 + lr;
            a[m] = *reinterpret_cast<const bf16x8*>(As + (rr << 9) + ((kc ^ (rr & 7)) << 4));
        }
        #pragma unroll
        for (int n = 0; n < 2; ++n) {
            int rr = wc * 32 + n * 16 + lr;
            b[n] = *reinterpret_cast<const bf16x8*>(Bs + (rr << 9) + ((kc ^ (rr & 7)) << 4));
        }
        #pragma unroll
        for (int m = 0; m < 4; ++m)
            #pragma unroll
            for (int n = 0; n < 2; ++n)
                acc[m][n] = __builtin_amdgcn_mfma_f32_16x16x32_bf16(a[m], b[n], acc[m][n], 0, 0, 0);
    }
    // C/D layout: col = lane&15, row = (lane>>4)*4 + reg

    // ---- tile max (raw, pre-relu) ----
    float mx = -3.4e38f;
    #pragma unroll
    for (int m = 0; m < 4; ++m)
        #pragma unroll
        for (int n = 0; n < 2; ++n)
            #pragma unroll
            for (int r = 0; r < 4; ++r)
                mx = fmaxf(mx, acc[m][n][r]);
    #pragma unroll
    for (int off = 32; off >= 1; off >>= 1)
        mx = fmaxf(mx, __shfl_xor(mx, off));

    // ---- col sums: reduce over rows (m, reg, lane-groups) ----
    float cs0 = 0.0f, cs1 = 0.0f;
    #pragma unroll
    for (int m = 0; m < 4; ++m)
        #pragma unroll
        for (int r = 0; r < 4; ++r) {
            cs0 += fmaxf(acc[m][0][r], 0.0f);
            cs1 += fmaxf(acc[m][1][r], 0.0f);
        }
    cs0 += __shfl_xor(cs0, 16); cs0 += __shfl_xor(cs0, 32);
    cs1 += __shfl_xor(cs1, 16); cs1 += __shfl_xor(cs1, 32);
    if (lane < 16) {
        int c0 = bcol + wc * 32 + lane;
        int c1 = c0 + 16;
        if (c0 < NPIX) atomicAdd(&col_sum[c0], cs0);
        if (c1 < NPIX) atomicAdd(&col_sum[c1], cs1);
    }

    // ---- row sums: per-lane partial over n, butterfly across the 16 col-lanes ----
    float rs[16];
    #pragma unroll
    for (int m = 0; m < 4; ++m)
        #pragma unroll
        for (int r = 0; r < 4; ++r)
            rs[m * 4 + r] = fmaxf(acc[m][0][r], 0.0f) + fmaxf(acc[m][1][r], 0.0f);
    #pragma unroll
    for (int off = 1; off <= 8; off <<= 1)
        #pragma unroll
        for (int j = 0; j < 16; ++j)
            rs[j] += __shfl_xor(rs[j], off);
    if (lr == 0) {
        int rbase = brow + wr * 64 + lg * 4;
        #pragma unroll
        for (int m = 0; m < 4; ++m)
            #pragma unroll
            for (int r = 0; r < 4; ++r) {
                int rowG = rbase + m * 16 + r;
                if (rowG < NPIX) atomicAdd(&row_sum[rowG], rs[m * 4 + r]);
            }
    }

    // ---- one atomicMax per block ----
    __syncthreads();
    float* smax = reinterpret_cast<float*>(lds);
    if (lane == 0) smax[wave] = mx;
    __syncthreads();
    if (tid == 0) {
        float m8 = smax[0];
        #pragma unroll
        for (int w = 1; w < 8; ++w) m8 = fmaxf(m8, smax[w]);
        atomicMax(max_u, fmono(m8));
    }
}

// Bilinear resize 2x72x72 -> 2x224x224 with final /max (resize is linear).
__global__ void finalize(const float* __restrict__ row_sum,
                         const float* __restrict__ col_sum,
                         const unsigned int* __restrict__ max_u,
                         float* __restrict__ out) {
    int o = blockIdx.x * blockDim.x + threadIdx.x;
    if (o >= 2 * OUTHW * OUTHW) return;
    int img = o / (OUTHW * OUTHW);
    int rem = o % (OUTHW * OUTHW);
    int oy = rem / OUTHW, ox = rem % OUTHW;
    const float* src = (img == 0) ? row_sum : col_sum;
    float inv = 1.0f / funmono(*max_u);

    const float s = 72.0f / 224.0f;
    float ys = fmaxf(((float)oy + 0.5f) * s - 0.5f, 0.0f);
    float xs = fmaxf(((float)ox + 0.5f) * s - 0.5f, 0.0f);
    int y0 = (int)floorf(ys), x0 = (int)floorf(xs);
    int y1 = min(y0 + 1, 71), x1 = min(x0 + 1, 71);
    float wy = ys - (float)y0, wx = xs - (float)x0;

    float a = src[y0 * 72 + x0], b = src[y0 * 72 + x1];
    float c = src[y1 * 72 + x0], d = src[y1 * 72 + x1];
    float v = a * (1.0f - wy) * (1.0f - wx) + b * (1.0f - wy) * wx
            + c * wy * (1.0f - wx)          + d * wy * wx;
    out[o] = v * inv;
}

extern "C" void kernel_launch(void* const* d_in, const int* in_sizes, int n_in,
                              void* d_out, int out_size, void* d_ws, size_t ws_size,
                              hipStream_t stream) {
    const float* X = (const float*)d_in[0];
    const size_t bf_bytes = (size_t)NPIX * KDIM * 2;            // 2,654,208 per matrix
    const size_t req = 2 * bf_bytes + 2 * NPIX * 4 + 16;
    float* out = (float*)d_out;

    if (ws_size >= req) {
        unsigned short* Abf = (unsigned short*)d_ws;
        unsigned short* Bbf = Abf + (size_t)NPIX * KDIM;
        float* row_sum      = (float*)((char*)d_ws + 2 * bf_bytes);
        float* col_sum      = row_sum + NPIX;
        unsigned int* max_u = (unsigned int*)(col_sum + NPIX);

        int n4 = 2 * NPIX * KDIM / 4;
        convert_bf16<<<(n4 + 255) / 256, 256, 0, stream>>>(X, Abf, row_sum, max_u, n4);
        gemm_reduce<true><<<1681, 512, 0, stream>>>(Abf, Bbf, row_sum, col_sum, max_u);
        finalize<<<(2 * OUTHW * OUTHW + 255) / 256, 256, 0, stream>>>(row_sum, col_sum, max_u, out);
    } else {
        float* row_sum      = (float*)d_ws;
        float* col_sum      = row_sum + NPIX;
        unsigned int* max_u = (unsigned int*)(col_sum + NPIX);

        init_ws<<<(2 * NPIX + 255) / 256, 256, 0, stream>>>(row_sum, max_u);
        gemm_reduce<false><<<1681, 512, 0, stream>>>(X, X + (size_t)NPIX * KDIM,
                                                     row_sum, col_sum, max_u);
        finalize<<<(2 * OUTHW * OUTHW + 255) / 256, 256, 0, stream>>>(row_sum, col_sum, max_u, out);
    }
}

// Round 3
// 48.782 us; speedup vs baseline: 2.4125x; 1.2129x over previous
//
#include <hip/hip_runtime.h>

#define NPIX 5184   // 72*72
#define KDIM 256
#define OUTHW 224
#define BT 192      // tile: 27*192 = 5184 exactly -> no edge handling
#define GRID_T 27
#define NWG 729
#define NKT 4       // K=256 in chunks of 64
#define MATB (BT*128)       // 24576 B: 192 rows x 64 bf16 (128 B) per matrix
#define BUFB (2*MATB)       // 49152 B per double-buffer slot (A+B)

typedef __bf16 bf16x8 __attribute__((ext_vector_type(8)));
typedef float  f32x4  __attribute__((ext_vector_type(4)));
typedef unsigned short u16x8 __attribute__((ext_vector_type(8)));

__device__ inline unsigned short f2bf(float f) {
    unsigned int b = __float_as_uint(f);
    b += 0x7FFFu + ((b >> 16) & 1u);     // round-to-nearest-even
    return (unsigned short)(b >> 16);
}
__device__ inline unsigned int fmono(float f) {
    unsigned int b = __float_as_uint(f);
    return b ^ ((b >> 31) ? 0xFFFFFFFFu : 0x80000000u);
}
__device__ inline float funmono(unsigned int u) {
    unsigned int b = u ^ ((u >> 31) ? 0x80000000u : 0xFFFFFFFFu);
    return __uint_as_float(b);
}

__global__ void init_ws(float* acc, unsigned int* max_u) {
    int i = blockIdx.x * blockDim.x + threadIdx.x;
    if (i < 2 * NPIX) acc[i] = 0.0f;
    if (i == 0) *max_u = 0u;
}

// fp32 -> bf16 for both matrices, fused with sums/max init.
__global__ void convert_bf16(const float* __restrict__ x, unsigned short* __restrict__ y,
                             float* __restrict__ sums, unsigned int* __restrict__ max_u,
                             int n4) {
    int i = blockIdx.x * blockDim.x + threadIdx.x;
    if (i < 2 * NPIX) sums[i] = 0.0f;
    if (i == 0) *max_u = 0u;
    if (i >= n4) return;
    float4 v = reinterpret_cast<const float4*>(x)[i];
    ushort4 u = { f2bf(v.x), f2bf(v.y), f2bf(v.z), f2bf(v.w) };
    reinterpret_cast<ushort4*>(y)[i] = u;
}

// D = A*B^T (5184^2, K=256), 192x192 tiles, 4 waves each owning 96x96.
// LDS: double-buffered K-chunks (BK=64). Chunk c (16B) of row r stored at
// slot c^(r&7) -> conflict-minimal ds_read_b128.
template<bool BF16IN>
__global__ __launch_bounds__(256, 1) void gemm_reduce(
        const void* __restrict__ Ain, const void* __restrict__ Bin,
        float* __restrict__ row_sum, float* __restrict__ col_sum,
        unsigned int* __restrict__ max_u) {
    __shared__ char lds[2 * BUFB];        // 96 KiB

    const int tid  = threadIdx.x;
    const int wave = tid >> 6, lane = tid & 63;

    // bijective XCD chunk swizzle (729 = 8*91 + 1)
    const int wg = blockIdx.x;
    const int q = NWG >> 3, r8 = NWG & 7;
    const int xcd = wg & 7, cidx = wg >> 3;
    const int swz = (xcd < r8) ? xcd * (q + 1) + cidx
                               : r8 * (q + 1) + (xcd - r8) * q + cidx;
    const int brow = (swz / GRID_T) * BT;
    const int bcol = (swz % GRID_T) * BT;

    const char*  Agc = (const char*)Ain;
    const char*  Bgc = (const char*)Bin;
    const float* Agf = (const float*)Ain;
    const float* Bgf = (const float*)Bin;

    // stage K-chunk t into buffer d (A+B). 12 gloads/wave (bf16 path).
    auto stage = [&](int t, int d) {
        char* Ab = lds + d * BUFB;
        char* Bb = Ab + MATB;
        if (BF16IN) {
            #pragma unroll
            for (int j = 0; j < 6; ++j) {
                int base = wave * 6144 + j * 1024;     // wave-uniform LDS dest
                int p    = base + lane * 16;
                int row  = p >> 7;
                int c    = ((p >> 4) & 7) ^ (row & 7); // pre-swizzled src chunk
                __builtin_amdgcn_global_load_lds(
                    (const __attribute__((address_space(1))) unsigned int*)
                        (Agc + (long)(brow + row) * 512 + t * 128 + (c << 4)),
                    (__attribute__((address_space(3))) unsigned int*)(Ab + base),
                    16, 0, 0);
                __builtin_amdgcn_global_load_lds(
                    (const __attribute__((address_space(1))) unsigned int*)
                        (Bgc + (long)(bcol + row) * 512 + t * 128 + (c << 4)),
                    (__attribute__((address_space(3))) unsigned int*)(Bb + base),
                    16, 0, 0);
            }
        } else {
            #pragma unroll
            for (int j = 0; j < 6; ++j) {
                int p   = j * 4096 + tid * 16;
                int row = p >> 7;
                int cg  = (p >> 4) & 7;
                int off = row * 128 + ((cg ^ (row & 7)) << 4);
                const float4* sA = (const float4*)(Agf + (long)(brow + row) * KDIM + t * 64 + cg * 8);
                const float4* sB = (const float4*)(Bgf + (long)(bcol + row) * KDIM + t * 64 + cg * 8);
                float4 a0 = sA[0], a1 = sA[1];
                float4 b0 = sB[0], b1 = sB[1];
                u16x8 ua = { f2bf(a0.x), f2bf(a0.y), f2bf(a0.z), f2bf(a0.w),
                             f2bf(a1.x), f2bf(a1.y), f2bf(a1.z), f2bf(a1.w) };
                u16x8 ub = { f2bf(b0.x), f2bf(b0.y), f2bf(b0.z), f2bf(b0.w),
                             f2bf(b1.x), f2bf(b1.y), f2bf(b1.z), f2bf(b1.w) };
                *reinterpret_cast<u16x8*>(Ab + off) = ua;
                *reinterpret_cast<u16x8*>(Bb + off) = ub;
            }
        }
    };

    // prologue: fill both buffers
    stage(0, 0);
    stage(1, 1);
    __syncthreads();

    const int wr = wave >> 1;   // 0..1
    const int wc = wave & 1;    // 0..1
    const int lr = lane & 15;
    const int lg = lane >> 4;   // 0..3

    f32x4 acc[6][6] = {};
    #pragma unroll
    for (int t = 0; t < NKT; ++t) {
        const char* Ab = lds + (t & 1) * BUFB;
        const char* Bb = Ab + MATB;
        #pragma unroll
        for (int ksl = 0; ksl < 2; ++ksl) {
            int kc = ksl * 4 + lg;
            bf16x8 a[6], b[6];
            #pragma unroll
            for (int m = 0; m < 6; ++m) {
                int r = wr * 96 + m * 16 + lr;
                a[m] = *reinterpret_cast<const bf16x8*>(Ab + r * 128 + ((kc ^ (r & 7)) << 4));
            }
            #pragma unroll
            for (int n = 0; n < 6; ++n) {
                int r = wc * 96 + n * 16 + lr;
                b[n] = *reinterpret_cast<const bf16x8*>(Bb + r * 128 + ((kc ^ (r & 7)) << 4));
            }
            #pragma unroll
            for (int m = 0; m < 6; ++m)
                #pragma unroll
                for (int n = 0; n < 6; ++n)
                    acc[m][n] = __builtin_amdgcn_mfma_f32_16x16x32_bf16(a[m], b[n], acc[m][n], 0, 0, 0);
        }
        __syncthreads();                 // vmcnt(0) drain is cheap: prefetch is a full step ahead
        if (t + 2 < NKT) stage(t + 2, t & 1);
    }

    // ---- fused reductions. C/D: col = lane&15, row = (lane>>4)*4 + reg ----
    float mx = -3.4e38f;
    float cs[6] = {};
    float rs[24] = {};
    #pragma unroll
    for (int m = 0; m < 6; ++m)
        #pragma unroll
        for (int n = 0; n < 6; ++n)
            #pragma unroll
            for (int r = 0; r < 4; ++r) {
                float v = acc[m][n][r];
                mx = fmaxf(mx, v);
                float rv = fmaxf(v, 0.0f);
                cs[n] += rv;
                rs[m * 4 + r] += rv;
            }

    // col sums: reduce over lane groups (rows)
    #pragma unroll
    for (int n = 0; n < 6; ++n) {
        cs[n] += __shfl_xor(cs[n], 16);
        cs[n] += __shfl_xor(cs[n], 32);
    }
    if (lane < 16) {
        #pragma unroll
        for (int n = 0; n < 6; ++n)
            atomicAdd(&col_sum[bcol + wc * 96 + n * 16 + lane], cs[n]);
    }

    // row sums: reduce over the 16 col-lanes within each lane group
    #pragma unroll
    for (int off = 1; off <= 8; off <<= 1)
        #pragma unroll
        for (int j = 0; j < 24; ++j)
            rs[j] += __shfl_xor(rs[j], off);
    if (lr == 0) {
        int rbase = brow + wr * 96 + lg * 4;
        #pragma unroll
        for (int m = 0; m < 6; ++m)
            #pragma unroll
            for (int r = 0; r < 4; ++r)
                atomicAdd(&row_sum[rbase + m * 16 + r], rs[m * 4 + r]);
    }

    // block max
    #pragma unroll
    for (int off = 32; off >= 1; off >>= 1)
        mx = fmaxf(mx, __shfl_xor(mx, off));
    float* smax = reinterpret_cast<float*>(lds);
    if (lane == 0) smax[wave] = mx;
    __syncthreads();
    if (tid == 0)
        atomicMax(max_u, fmono(fmaxf(fmaxf(smax[0], smax[1]), fmaxf(smax[2], smax[3]))));
}

// Bilinear resize 2x72x72 -> 2x224x224 with final /max (resize is linear).
__global__ void finalize(const float* __restrict__ row_sum,
                         const float* __restrict__ col_sum,
                         const unsigned int* __restrict__ max_u,
                         float* __restrict__ out) {
    int o = blockIdx.x * blockDim.x + threadIdx.x;
    if (o >= 2 * OUTHW * OUTHW) return;
    int img = o / (OUTHW * OUTHW);
    int rem = o % (OUTHW * OUTHW);
    int oy = rem / OUTHW, ox = rem % OUTHW;
    const float* src = (img == 0) ? row_sum : col_sum;
    float inv = 1.0f / funmono(*max_u);

    const float s = 72.0f / 224.0f;
    float ys = fmaxf(((float)oy + 0.5f) * s - 0.5f, 0.0f);
    float xs = fmaxf(((float)ox + 0.5f) * s - 0.5f, 0.0f);
    int y0 = (int)floorf(ys), x0 = (int)floorf(xs);
    int y1 = min(y0 + 1, 71), x1 = min(x0 + 1, 71);
    float wy = ys - (float)y0, wx = xs - (float)x0;

    float a = src[y0 * 72 + x0], b = src[y0 * 72 + x1];
    float c = src[y1 * 72 + x0], d = src[y1 * 72 + x1];
    float v = a * (1.0f - wy) * (1.0f - wx) + b * (1.0f - wy) * wx
            + c * wy * (1.0f - wx)          + d * wy * wx;
    out[o] = v * inv;
}

extern "C" void kernel_launch(void* const* d_in, const int* in_sizes, int n_in,
                              void* d_out, int out_size, void* d_ws, size_t ws_size,
                              hipStream_t stream) {
    const float* X = (const float*)d_in[0];
    const size_t bf_bytes = (size_t)NPIX * KDIM * 2;
    const size_t req = 2 * bf_bytes + 2 * NPIX * 4 + 16;
    float* out = (float*)d_out;

    if (ws_size >= req) {
        unsigned short* Abf = (unsigned short*)d_ws;
        unsigned short* Bbf = Abf + (size_t)NPIX * KDIM;
        float* row_sum      = (float*)((char*)d_ws + 2 * bf_bytes);
        float* col_sum      = row_sum + NPIX;
        unsigned int* max_u = (unsigned int*)(col_sum + NPIX);

        int n4 = 2 * NPIX * KDIM / 4;
        convert_bf16<<<(n4 + 255) / 256, 256, 0, stream>>>(X, Abf, row_sum, max_u, n4);
        gemm_reduce<true><<<NWG, 256, 0, stream>>>(Abf, Bbf, row_sum, col_sum, max_u);
        finalize<<<(2 * OUTHW * OUTHW + 255) / 256, 256, 0, stream>>>(row_sum, col_sum, max_u, out);
    } else {
        float* row_sum      = (float*)d_ws;
        float* col_sum      = row_sum + NPIX;
        unsigned int* max_u = (unsigned int*)(col_sum + NPIX);

        init_ws<<<(2 * NPIX + 255) / 256, 256, 0, stream>>>(row_sum, max_u);
        gemm_reduce<false><<<NWG, 256, 0, stream>>>(X, X + (size_t)NPIX * KDIM,
                                                    row_sum, col_sum, max_u);
        finalize<<<(2 * OUTHW * OUTHW + 255) / 256, 256, 0, stream>>>(row_sum, col_sum, max_u, out);
    }
}